// Round 1
// baseline (55403.271 us; speedup 1.0000x reference)
//
#include <hip/hip_runtime.h>

#define SS 16384
#define DD 1024
#define HH 1024
#define G4H 4096

typedef unsigned long long u64;
typedef unsigned int u32;
typedef unsigned short ushort_t;

typedef __attribute__((ext_vector_type(8))) short bf16x8;
typedef __attribute__((ext_vector_type(4))) float f32x4;

__device__ __forceinline__ float sigm(float x){ return 1.0f/(1.0f+__expf(-x)); }
__device__ __forceinline__ float tanh_fast(float x){ return 1.0f - 2.0f/(__expf(2.0f*x)+1.0f); }

__device__ __forceinline__ ushort_t f2bf(float f){
    u32 u = __float_as_uint(f);
    u32 r = (u + 0x7FFFu + ((u>>16)&1u)) >> 16;
    return (ushort_t)r;
}

// ---------------- prep: fp32 -> bf16 conversions + bias ----------------
__global__ __launch_bounds__(256) void prep_kernel(
    const float* __restrict__ x, const float* __restrict__ wih,
    const float* __restrict__ bih, const float* __restrict__ bhh,
    ushort_t* __restrict__ xb, ushort_t* __restrict__ wb, float* __restrict__ bias)
{
    long long i = (long long)blockIdx.x*256 + threadIdx.x;
    const long long NX = (long long)SS*DD;      // 16777216
    const long long NW = (long long)G4H*DD;     // 4194304
    if (i < NX) { xb[i] = f2bf(x[i]); }
    else if (i < NX+NW) { long long j=i-NX; wb[j]=f2bf(wih[j]); }
    else { int j=(int)(i-NX-NW); if (j < G4H) bias[j]=bih[j]+bhh[j]; }
}

// ---------------- GEMM: xg = x @ W_ih^T + bias, fp16 out ----------------
#define LDA 40  // padded LDS row stride (bf16 elems)

__global__ __launch_bounds__(256) void gemm_kernel(
    const ushort_t* __restrict__ A, const ushort_t* __restrict__ B,
    const float* __restrict__ bias, _Float16* __restrict__ Cg)
{
    __shared__ ushort_t At[128*LDA];
    __shared__ ushort_t Bt[128*LDA];
    const int tid  = threadIdx.x;
    const int lane = tid & 63;
    const int wv   = tid >> 6;
    const int wm   = wv >> 1, wn = wv & 1;
    const int m0   = blockIdx.y * 128;
    const int n0   = blockIdx.x * 128;
    const int quad = lane >> 4;
    const int l16  = lane & 15;

    f32x4 acc[4][4];
    #pragma unroll
    for (int a=0;a<4;a++)
      #pragma unroll
      for (int b=0;b<4;b++) acc[a][b] = (f32x4){0.f,0.f,0.f,0.f};

    for (int kb = 0; kb < DD; kb += 32) {
        #pragma unroll
        for (int s=0;s<2;s++){
            int ch  = tid*2+s;            // 0..511
            int row = ch >> 2;
            int ko  = (ch & 3) * 8;
            uint4 va = *(const uint4*)(A + (long long)(m0+row)*DD + kb + ko);
            *(uint4*)(At + row*LDA + ko) = va;
            uint4 vb = *(const uint4*)(B + (long long)(n0+row)*DD + kb + ko);
            *(uint4*)(Bt + row*LDA + ko) = vb;
        }
        __syncthreads();
        bf16x8 af[4], bfr[4];
        #pragma unroll
        for (int mi=0;mi<4;mi++){
            int r = wm*64 + mi*16 + l16;
            af[mi] = *(const bf16x8*)(At + r*LDA + quad*8);
        }
        #pragma unroll
        for (int ni=0;ni<4;ni++){
            int r = wn*64 + ni*16 + l16;
            bfr[ni] = *(const bf16x8*)(Bt + r*LDA + quad*8);
        }
        #pragma unroll
        for (int mi=0;mi<4;mi++)
          #pragma unroll
          for (int ni=0;ni<4;ni++)
            acc[mi][ni] = __builtin_amdgcn_mfma_f32_16x16x32_bf16(af[mi], bfr[ni], acc[mi][ni], 0,0,0);
        __syncthreads();
    }
    #pragma unroll
    for (int mi=0;mi<4;mi++){
      #pragma unroll
      for (int ni=0;ni<4;ni++){
        int col = n0 + wn*64 + ni*16 + l16;
        float bv = bias[col];
        #pragma unroll
        for (int r=0;r<4;r++){
            int rowg = m0 + wm*64 + mi*16 + quad*4 + r;
            Cg[(long long)rowg*G4H + col] = (_Float16)(acc[mi][ni][r] + bv);
        }
      }
    }
}

// ---------------- persistent LSTM scan ----------------
#define SENT 0xFFFFFFFFFFFFFFFFull
__device__ __forceinline__ int pidx(int i){ return i + (i>>4); }

__global__ __launch_bounds__(256, 1) void scan_kernel(
    const float* __restrict__ whh, const _Float16* __restrict__ xg,
    u64* __restrict__ packed)
{
    __shared__ float h_lds[1024 + 64];
    __shared__ float gsum[2][16];
    __shared__ float xg_lds[16];
    const int w    = blockIdx.x;     // 0..255  -> owns hidden units 4w..4w+3
    const int tid  = threadIdx.x;
    const int lane = tid & 63;
    const int wv   = tid >> 6;       // gate index for this wave (i,f,g,o)
    const int hu0  = w*4;

    // W_hh slice in registers: rows wv*H + hu0 + k, cols 16*lane + j
    float Wr[4][16];
    #pragma unroll
    for (int k=0;k<4;k++){
        const float* rp = whh + (long long)(wv*HH + hu0 + k)*HH + 16*lane;
        #pragma unroll
        for (int q=0;q<4;q++){
            float4 v = *(const float4*)(rp + 4*q);
            Wr[k][4*q+0]=v.x; Wr[k][4*q+1]=v.y; Wr[k][4*q+2]=v.z; Wr[k][4*q+3]=v.w;
        }
    }

    float c_st = 0.0f;     // cell state (wave 0, lanes 0..3)
    float xgp  = 0.0f;     // prefetched xg value (tid<16)
    if (tid < 16) xgp = (float)xg[(long long)(tid>>2)*HH + hu0 + (tid&3)];

    for (int t=0; t<SS; ++t){
        if (tid < 16) xg_lds[tid] = xgp;
        if (t == 0){
            #pragma unroll
            for (int j=0;j<4;j++) h_lds[pidx(4*tid+j)] = 0.0f;
        } else {
            const u64* src = &packed[(long long)(t-1)*256 + tid];
            u64 v = __hip_atomic_load(src, __ATOMIC_RELAXED, __HIP_MEMORY_SCOPE_AGENT);
            int spin = 0;
            while (v == SENT){
                __builtin_amdgcn_s_sleep(1);
                v = __hip_atomic_load(src, __ATOMIC_RELAXED, __HIP_MEMORY_SCOPE_AGENT);
                if (++spin > (1<<21)) break;   // deadlock insurance
            }
            union { u64 u; _Float16 h[4]; } cv; cv.u = v;
            #pragma unroll
            for (int j=0;j<4;j++) h_lds[pidx(4*tid+j)] = (float)cv.h[j];
        }
        __syncthreads();
        // prefetch next step's xg while compute proceeds
        if (tid < 16 && t+1 < SS)
            xgp = (float)xg[(long long)(t+1)*G4H + (tid>>2)*HH + hu0 + (tid&3)];
        // partial dots: 4 rows (units) for this wave's gate
        float s0=0.f,s1=0.f,s2=0.f,s3=0.f;
        #pragma unroll
        for (int j=0;j<16;j++){
            float hv = h_lds[pidx(16*lane+j)];
            s0 += Wr[0][j]*hv; s1 += Wr[1][j]*hv;
            s2 += Wr[2][j]*hv; s3 += Wr[3][j]*hv;
        }
        #pragma unroll
        for (int off=32; off>=1; off>>=1){
            s0 += __shfl_xor(s0, off, 64);
            s1 += __shfl_xor(s1, off, 64);
            s2 += __shfl_xor(s2, off, 64);
            s3 += __shfl_xor(s3, off, 64);
        }
        const int par = t & 1;
        if (lane == 0){
            gsum[par][wv*4+0]=s0; gsum[par][wv*4+1]=s1;
            gsum[par][wv*4+2]=s2; gsum[par][wv*4+3]=s3;
        }
        __syncthreads();
        if (wv == 0){
            float hval = 0.0f;
            if (lane < 4){
                int k = lane;
                float zi = gsum[par][0+k]  + xg_lds[0+k];
                float zf = gsum[par][4+k]  + xg_lds[4+k];
                float zg = gsum[par][8+k]  + xg_lds[8+k];
                float zo = gsum[par][12+k] + xg_lds[12+k];
                c_st = sigm(zf)*c_st + sigm(zi)*tanh_fast(zg);
                hval = sigm(zo)*tanh_fast(c_st);
            }
            float h0 = __shfl(hval, 0, 64);
            float h1 = __shfl(hval, 1, 64);
            float h2 = __shfl(hval, 2, 64);
            float h3 = __shfl(hval, 3, 64);
            if (lane == 0){
                union { u64 u; _Float16 h[4]; } pk;
                pk.h[0]=(_Float16)h0; pk.h[1]=(_Float16)h1;
                pk.h[2]=(_Float16)h2; pk.h[3]=(_Float16)h3;
                __hip_atomic_store(&packed[(long long)t*256 + w], pk.u,
                                   __ATOMIC_RELAXED, __HIP_MEMORY_SCOPE_AGENT);
            }
        }
    }
}

// ---------------- alpha = sigmoid(hs @ W_fc^T + b_fc) ----------------
__global__ __launch_bounds__(256) void alpha_kernel(
    const u64* __restrict__ packed, const float* __restrict__ wfc,
    const float* __restrict__ bfc, float* __restrict__ alpha)
{
    int row  = blockIdx.x*4 + (threadIdx.x>>6);
    int lane = threadIdx.x & 63;
    const u64* p = packed + (long long)row*256 + 4*lane;
    float s = 0.f;
    #pragma unroll
    for (int q=0;q<4;q++){
        union { u64 u; _Float16 h[4]; } cv; cv.u = p[q];
        float4 wvv = *(const float4*)(wfc + 16*lane + 4*q);
        s += (float)cv.h[0]*wvv.x + (float)cv.h[1]*wvv.y
           + (float)cv.h[2]*wvv.z + (float)cv.h[3]*wvv.w;
    }
    #pragma unroll
    for (int off=32; off>=1; off>>=1) s += __shfl_xor(s, off, 64);
    if (lane==0) alpha[row] = sigm(s + bfc[0]);
}

// ---------------- finalize: affine scans + loss ----------------
__global__ __launch_bounds__(256) void finalize_kernel(
    const float* __restrict__ uttr_pred, const float* __restrict__ timing_label,
    const float* __restrict__ alpha, float* __restrict__ out)
{
    const int n = SS-1;  // 16383
    const int tid = threadIdx.x;
    __shared__ float Ms[256], Cs[256], Pre[256];
    __shared__ int Fi[256];
    float* out_y = out + 1;
    float* out_a = out + 1 + n;
    float* out_u = out + 1 + 2*n;

    int i0 = tid*64;
    int i1 = i0+64; if (i1 > n) i1 = n;

    // pass 1: u, a-scan chunk composition, first mask index
    float M = 1.f, C = 0.f;
    int fi = 0x7fffffff;
    for (int i=i0; i<i1; ++i){
        float u = 1.f - uttr_pred[i+1];
        float a = alpha[i+1];
        out_u[i] = u;
        M = u*M;
        C = u*C + (1.f-u)*a;
        if (timing_label[i] > 0.8f && i < fi) fi = i;
    }
    Ms[tid]=M; Cs[tid]=C; Fi[tid]=fi;
    __syncthreads();
    if (tid==0){
        float x=0.f;
        for (int tt=0; tt<256; ++tt){ Pre[tt]=x; x = Ms[tt]*x + Cs[tt]; }
        int best=0x7fffffff;
        for (int tt=0; tt<256; ++tt) best = min(best, Fi[tt]);
        Fi[0]=best;
    }
    __syncthreads();
    // pass 2: emit a_seq, compose y-scan chunks
    float x = Pre[tid];
    float My=1.f, Cy=0.f;
    for (int i=i0;i<i1;++i){
        float u = 1.f - uttr_pred[i+1];
        float a = alpha[i+1];
        x = u*x + (1.f-u)*a;
        out_a[i] = x;
        float Af = 1.f - x;
        float Bf = x*u;
        My = Af*My;
        Cy = Af*Cy + Bf;
    }
    Ms[tid]=My; Cs[tid]=Cy;
    __syncthreads();
    if (tid==0){
        float y=0.f;
        for (int tt=0;tt<256;++tt){ Pre[tt]=y; y = Ms[tt]*y + Cs[tt]; }
    }
    __syncthreads();
    float y = Pre[tid];
    for (int i=i0;i<i1;++i){
        float ag = out_a[i];
        float u  = out_u[i];
        y = ag*u + (1.f-ag)*y;
        out_y[i] = y;
    }
    __syncthreads();
    if (tid==0){
        int best = Fi[0];
        bool exists = (best != 0x7fffffff);
        int idx = exists ? best : 0;
        float u_at = 1.f - uttr_pred[idx+1];
        float y_at = out_y[idx];
        float y_last = out_y[n-1];
        float loss;
        if (exists) loss = (u_at < 0.5f) ? 0.f : (y_at-0.8f)*(y_at-0.8f);
        else        loss = (y_last >= 0.8f) ? (y_last-0.4f)*(y_last-0.4f) : 0.f;
        out[0] = loss;
    }
}

// ---------------- launch ----------------
extern "C" void kernel_launch(void* const* d_in, const int* in_sizes, int n_in,
                              void* d_out, int out_size, void* d_ws, size_t ws_size,
                              hipStream_t stream)
{
    const float* x    = (const float*)d_in[0];
    const float* up   = (const float*)d_in[1];
    const float* tl   = (const float*)d_in[2];
    // d_in[3] = uttr_label (unused by the math)
    const float* wih  = (const float*)d_in[4];
    const float* whh  = (const float*)d_in[5];
    const float* bih  = (const float*)d_in[6];
    const float* bhh  = (const float*)d_in[7];
    const float* wfc  = (const float*)d_in[8];
    const float* bfc  = (const float*)d_in[9];
    float* out = (float*)d_out;

    char* ws = (char*)d_ws;
    ushort_t* xb   = (ushort_t*)(ws);                      // 32 MB  x bf16
    ushort_t* wb   = (ushort_t*)(ws + 33554432);           //  8 MB  W_ih bf16
    _Float16* xg   = (_Float16*)(ws + 41943040);           // 128 MB xg fp16
    u64*      pkd  = (u64*)     (ws + 176160768);          // 32 MB  packed h history
    float*    alp  = (float*)   (ws + 209715200);          // 64 KB  alpha
    float*    bias = (float*)   (ws + 209780736);          // 16 KB  bias

    hipMemsetAsync(pkd, 0xFF, (size_t)SS*HH*2, stream);    // sentinel init
    prep_kernel<<<81936, 256, 0, stream>>>(x, wih, bih, bhh, xb, wb, bias);
    gemm_kernel<<<dim3(G4H/128, SS/128), 256, 0, stream>>>(xb, wb, bias, xg);
    scan_kernel<<<256, 256, 0, stream>>>(whh, xg, pkd);
    alpha_kernel<<<SS/4, 256, 0, stream>>>(pkd, wfc, bfc, alp);
    finalize_kernel<<<1, 256, 0, stream>>>(up, tl, alp, out);
}